// Round 7
// baseline (105.972 us; speedup 1.0000x reference)
//
#include <hip/hip_runtime.h>

// Problem constants
#define NIMG 4
#define CCH  3
#define KCH  21
#define HIN  128
#define WIN  128
#define OH   64
#define OW   64
#define PPX  (OH*OW)          // 4096 pixels after 0.5x downsample
#define NPIX (NIMG*PPX)       // 16384 = 2^14

// feature prescale: sqrt(2)*sqrt(0.5*log2(e)) so that
//   exp(-0.5*d2) == exp2( v_i . v_j - h_i - h_j ),  h = 0.5*|v|^2
#define PRE2 1.20112241f

#define SEGW  24              // halfs per pixel: 21 seg + 3 zero (48B)
#define FEATW 8               // halfs per pixel: 5 feat + 3 zero (16B)

#define BLOCK  256
#define JCHUNK 256            // j-pixels staged per block
#define IBLK   64             // i-pixels per block (16 per wave)

#define NSLOT  64             // partial-sum cachelines (atomic spreading)
#define NBLK_MAIN (544*NIMG)  // 2176 main blocks

typedef _Float16 half_t;
typedef half_t half8  __attribute__((ext_vector_type(8)));
typedef float  f32x4v __attribute__((ext_vector_type(4)));

// ws layout (bytes): segH | featH | sqF | slots | counter
#define FEATH_OFF ((size_t)NPIX*SEGW*2)
#define SQF_OFF   (FEATH_OFF + (size_t)NPIX*FEATW*2)
#define SLOT_OFF  (SQF_OFF + (size_t)NPIX*4)
#define CNT_OFF   (SLOT_OFF + (size_t)NSLOT*16*4)

// ---------------------------------------------------------------------------
// Prep: pixel-fast indexing (g = q*NPIX + pl) so every global read is a
// 64-lane x 8B contiguous segment and featH/sqF writes coalesce.
// q<24 -> seg channel (2x2 avg pool * nearest ROI) as f16;
// q==24 -> 5 prescaled features as f16 (padded half8) + fp32 h = 0.5|v|^2
// from the f16-ROUNDED v so E_ii == 0 exactly.
// q==25, pl<64 -> zero slots; pl==64 -> zero the done-counter.
// ---------------------------------------------------------------------------
__global__ __launch_bounds__(BLOCK) void crf_prep(const float* __restrict__ img,
                                                  const float* __restrict__ seg,
                                                  const float* __restrict__ roi,
                                                  half_t* __restrict__ segH,
                                                  half_t* __restrict__ featH,
                                                  float* __restrict__ sqF,
                                                  float* __restrict__ slots,
                                                  unsigned* __restrict__ counter) {
    int g  = blockIdx.x * BLOCK + threadIdx.x;    // [0, 32*NPIX)
    int q  = g >> 14;                             // slow: record element
    int pl = g & (NPIX - 1);                      // fast: linear pixel
    int n  = pl >> 12;
    int p  = pl & (PPX - 1);
    int y = p >> 6, x = p & 63;
    int y2 = 2 * y, x2 = 2 * x;

    if (q < SEGW) {
        float v = 0.0f;
        if (q < KCH) {
            const float* s0 = seg + (((size_t)n * KCH + q) * HIN + y2) * WIN + x2;
            float r = roi[((size_t)n * HIN + y2) * WIN + x2];
            v = 0.25f * (s0[0] + s0[1] + s0[WIN] + s0[WIN + 1]) * r;
        }
        segH[(size_t)pl * SEGW + q] = (half_t)v;
    } else if (q == 24) {
        float fx = (float)x * (PRE2 / 50.0f);
        float fy = (float)y * (PRE2 / 50.0f);
        const size_t ib = (((size_t)n * CCH) * HIN + y2) * WIN + x2;
        float fr = img[ib]                         * (PRE2 / 0.15f);
        float fg = img[ib + (size_t)HIN * WIN]     * (PRE2 / 0.15f);
        float fb = img[ib + 2 * (size_t)HIN * WIN] * (PRE2 / 0.15f);
        half_t h0 = (half_t)fx, h1 = (half_t)fy, h2 = (half_t)fr,
               h3 = (half_t)fg, h4 = (half_t)fb;
        half8 fh = {h0, h1, h2, h3, h4, (half_t)0, (half_t)0, (half_t)0};
        *(half8*)(featH + (size_t)pl * FEATW) = fh;
        float a0 = (float)h0, a1 = (float)h1, a2 = (float)h2,
              a3 = (float)h3, a4 = (float)h4;
        sqF[pl] = 0.5f * (a0 * a0 + a1 * a1 + a2 * a2 + a3 * a3 + a4 * a4);
    } else if (q == 25) {
        if (pl < NSLOT) slots[pl * 16] = 0.0f;    // one slot per cacheline
        if (pl == NSLOT) *counter = 0u;
    }
}

// ---------------------------------------------------------------------------
// Main: per 16x16 pair tile, two mfma_f32_16x16x32_f16:
//   E  = mfma(afeat, bfeat, c4)   with c4[r] = -h_i(row r) - h_j(col)
//   Gs = mfma(aseg,  bseg,  0)
//   term = exp2(E) * Gs     (diag blocks add {+1,0,-inf} in log2 space)
// Partials -> 64 spread cachelines; the LAST block to finish (device-scope
// counter) re-reads the slots with agent-scope atomic loads (cross-XCD
// coherent) and writes the scalar output. No separate final kernel.
// ---------------------------------------------------------------------------
__global__ __launch_bounds__(BLOCK) void crf_main(const half_t* __restrict__ segH,
                                                  const half_t* __restrict__ featH,
                                                  const float* __restrict__ sqF,
                                                  float* __restrict__ slots,
                                                  unsigned* __restrict__ counter,
                                                  float* __restrict__ out) {
    const int bx = blockIdx.x;
    const int n  = blockIdx.y;

    // triangular decode: g = I>>2 group; 4 I's per group, 16-g J's each
    int g = 0;
#pragma unroll
    for (int t = 1; t < 16; ++t) {
        int off = 64 * t - 2 * t * (t - 1);
        if (bx >= off) g = t;
    }
    int rem = bx - (64 * g - 2 * g * (g - 1));
    int c   = 16 - g;
    int iq  = (rem >= c) + (rem >= 2 * c) + (rem >= 3 * c);
    int I   = 4 * g + iq;
    int J   = g + (rem - iq * c);
    const bool diag = (J == (I >> 2));

    const half_t* segN  = segH  + (size_t)n * PPX * SEGW;
    const half_t* featN = featH + (size_t)n * PPX * FEATW;
    const float*  sqN   = sqF   + (size_t)n * PPX;

    __shared__ alignas(16) half_t segJ[JCHUNK * SEGW];    // 12 KB
    __shared__ alignas(16) half_t featJ[JCHUNK * FEATW];  // 4 KB
    __shared__ alignas(16) half_t zrow[8];                // 16 B of zeros
    __shared__ float hJ[JCHUNK];                          // 1 KB
    __shared__ float wsum[BLOCK / 64];
    __shared__ int   lastFlag;

    const int tid  = threadIdx.x;
    const int lane = tid & 63, wv = tid >> 6;
    const int m = lane & 15, quad = lane >> 4;
    const int i0 = I * IBLK + wv * 16;
    const int j0 = J * JCHUNK;
    const int kq = (quad < 2) ? quad : 2;   // seg k-slice (quad3 -> zero row)

    half8 hz = {};

    // A-frags from global (reused over all 16 j-tiles)
    half8 aseg  = *(const half8*)(segN  + (size_t)(i0 + m) * SEGW + kq * 8);
    half8 afeat = *(const half8*)(featN + (size_t)(i0 + m) * FEATW);
    f32x4v hi   = *(const f32x4v*)(sqN + i0 + quad * 4);  // rows quad*4..+3
    if (quad == 3) aseg  = hz;
    if (quad != 0) afeat = hz;
    f32x4v nh = -hi;

    // stage j-chunk (flat coalesced 16B copies) + zero row
    {
        const f32x4v* gsrc = (const f32x4v*)(segN + (size_t)j0 * SEGW);
        f32x4v* ldst = (f32x4v*)segJ;
#pragma unroll
        for (int v = 0; v < 3; ++v) ldst[tid + v * BLOCK] = gsrc[tid + v * BLOCK];
        ((f32x4v*)featJ)[tid] = ((const f32x4v*)(featN + (size_t)j0 * FEATW))[tid];
        hJ[tid] = sqN[j0 + tid];
        if (tid < 8) zrow[tid] = (half_t)0;
    }
    __syncthreads();

    // per-lane B pointers: stride over j-tiles, or pinned to the zero row
    const half_t* bsp; int bstep;
    if (quad == 3) { bsp = zrow;                       bstep = 0; }
    else           { bsp = segJ + m * SEGW + quad * 8; bstep = 16 * SEGW; }
    const half_t* bfp; int fstep;
    if (quad == 0) { bfp = featJ + m * FEATW;          fstep = 16 * FEATW; }
    else           { bfp = zrow;                       fstep = 0; }

    float racc = 0.0f;
    const f32x4v zero4 = {0.0f, 0.0f, 0.0f, 0.0f};

#pragma unroll 4
    for (int jt = 0; jt < JCHUNK / 16; ++jt) {
        half8 bseg = *(const half8*)bsp;  bsp += bstep;
        half8 bft  = *(const half8*)bfp;  bfp += fstep;
        float hc = hJ[jt * 16 + m];

        f32x4v c4 = {nh[0] - hc, nh[1] - hc, nh[2] - hc, nh[3] - hc};
        f32x4v E  = __builtin_amdgcn_mfma_f32_16x16x32_f16(afeat, bft, c4, 0, 0, 0);
        f32x4v Gs = __builtin_amdgcn_mfma_f32_16x16x32_f16(aseg, bseg, zero4, 0, 0, 0);

        if (!diag) {
#pragma unroll
            for (int r = 0; r < 4; ++r)
                racc = fmaf(__builtin_amdgcn_exp2f(E[r]), Gs[r], racc);
        } else {
            const int jg = j0 + jt * 16 + m;
#pragma unroll
            for (int r = 0; r < 4; ++r) {
                int ig = i0 + quad * 4 + r;
                float sel = (jg > ig) ? 1.0f : ((jg == ig) ? 0.0f : -100000.0f);
                racc = fmaf(__builtin_amdgcn_exp2f(E[r] + sel), Gs[r], racc);
            }
        }
    }

    // reduce: thread -> wave -> block -> spread atomic slot
#pragma unroll
    for (int off = 32; off > 0; off >>= 1) racc += __shfl_down(racc, off);
    if (lane == 0) wsum[wv] = racc;
    __syncthreads();
    if (tid == 0) {
        float s = wsum[0] + wsum[1] + wsum[2] + wsum[3];
        if (!diag) s *= 2.0f;              // strictly-upper counts (i,j)+(j,i)
        int slot = (bx + 544 * n) & (NSLOT - 1);
        atomicAdd(&slots[slot * 16], s);   // device-scope
        __threadfence();                   // partial visible before counter inc
        unsigned old = atomicAdd(counter, 1u);
        lastFlag = (old == NBLK_MAIN - 1) ? 1 : 0;
    }
    __syncthreads();

    // last block: gather the 64 slots (agent-scope atomic loads) -> scalar out
    if (lastFlag && wv == 0) {
        float v = __hip_atomic_load(&slots[lane * 16], __ATOMIC_RELAXED,
                                    __HIP_MEMORY_SCOPE_AGENT);
#pragma unroll
        for (int off = 32; off > 0; off >>= 1) v += __shfl_down(v, off);
        if (lane == 0) out[0] = v * (-5.0e-10f);   // WEIGHT * (-sum/NIMG)
    }
}

extern "C" void kernel_launch(void* const* d_in, const int* in_sizes, int n_in,
                              void* d_out, int out_size, void* d_ws, size_t ws_size,
                              hipStream_t stream) {
    const float* img = (const float*)d_in[0];
    const float* seg = (const float*)d_in[1];
    const float* roi = (const float*)d_in[2];
    float* out = (float*)d_out;

    char* wsb = (char*)d_ws;                    // ~1.07 MB of ws used
    half_t* segH  = (half_t*)(wsb);
    half_t* featH = (half_t*)(wsb + FEATH_OFF);
    float*  sqF   = (float*)(wsb + SQF_OFF);
    float*  slots = (float*)(wsb + SLOT_OFF);
    unsigned* cnt = (unsigned*)(wsb + CNT_OFF);

    crf_prep<<<(NPIX * 32) / BLOCK, BLOCK, 0, stream>>>(img, seg, roi,
                                                        segH, featH, sqF, slots, cnt);

    dim3 grid(544, NIMG);                       // sum_g 4*(16-g) = 544 per image
    crf_main<<<grid, BLOCK, 0, stream>>>(segH, featH, sqF, slots, cnt, out);
}

// Round 8
// 76.422 us; speedup vs baseline: 1.3867x; 1.3867x over previous
//
#include <hip/hip_runtime.h>

// Problem constants
#define NIMG 4
#define CCH  3
#define KCH  21
#define HIN  128
#define WIN  128
#define OH   64
#define OW   64
#define PPX  (OH*OW)          // 4096 pixels after 0.5x downsample
#define NPIX (NIMG*PPX)       // 16384 = 2^14

// feature prescale: sqrt(2)*sqrt(0.5*log2(e)) so that
//   exp(-0.5*d2) == exp2( v_i . v_j - h_i - h_j ),  h = 0.5*|v|^2
#define PRE2 1.20112241f

#define SEGW  24              // halfs per pixel: 21 seg + 3 zero (48B)
#define FEATW 8               // halfs per pixel: 5 feat + 3 zero (16B)

#define BLOCK  256
#define JCHUNK 256            // j-pixels staged per block
#define IBLK   64             // i-pixels per block (16 per wave)

#define NSLOT  64             // partial-sum cachelines (atomic spreading)

typedef _Float16 half_t;
typedef half_t half8  __attribute__((ext_vector_type(8)));
typedef float  f32x4v __attribute__((ext_vector_type(4)));

// ws layout (bytes): segH | featH | sqF | slots
#define FEATH_OFF ((size_t)NPIX*SEGW*2)
#define SQF_OFF   (FEATH_OFF + (size_t)NPIX*FEATW*2)
#define SLOT_OFF  (SQF_OFF + (size_t)NPIX*4)

// ---------------------------------------------------------------------------
// Prep: pixel-fast indexing (g = q*NPIX + pl) so every global read is a
// 64-lane contiguous segment and featH/sqF writes coalesce.
// q<24 -> seg channel (2x2 avg pool * nearest ROI) as f16;
// q==24 -> 5 prescaled features as f16 (padded half8) + fp32 h = 0.5|v|^2
// from the f16-ROUNDED v so E_ii == 0 exactly.
// q==25, pl<64 -> zero the partial-sum slots.
// ---------------------------------------------------------------------------
__global__ __launch_bounds__(BLOCK) void crf_prep(const float* __restrict__ img,
                                                  const float* __restrict__ seg,
                                                  const float* __restrict__ roi,
                                                  half_t* __restrict__ segH,
                                                  half_t* __restrict__ featH,
                                                  float* __restrict__ sqF,
                                                  float* __restrict__ slots) {
    int g  = blockIdx.x * BLOCK + threadIdx.x;    // [0, 32*NPIX)
    int q  = g >> 14;                             // slow: record element
    int pl = g & (NPIX - 1);                      // fast: linear pixel
    int n  = pl >> 12;
    int p  = pl & (PPX - 1);
    int y = p >> 6, x = p & 63;
    int y2 = 2 * y, x2 = 2 * x;

    if (q < SEGW) {
        float v = 0.0f;
        if (q < KCH) {
            const float* s0 = seg + (((size_t)n * KCH + q) * HIN + y2) * WIN + x2;
            float r = roi[((size_t)n * HIN + y2) * WIN + x2];
            v = 0.25f * (s0[0] + s0[1] + s0[WIN] + s0[WIN + 1]) * r;
        }
        segH[(size_t)pl * SEGW + q] = (half_t)v;
    } else if (q == 24) {
        float fx = (float)x * (PRE2 / 50.0f);
        float fy = (float)y * (PRE2 / 50.0f);
        const size_t ib = (((size_t)n * CCH) * HIN + y2) * WIN + x2;
        float fr = img[ib]                         * (PRE2 / 0.15f);
        float fg = img[ib + (size_t)HIN * WIN]     * (PRE2 / 0.15f);
        float fb = img[ib + 2 * (size_t)HIN * WIN] * (PRE2 / 0.15f);
        half_t h0 = (half_t)fx, h1 = (half_t)fy, h2 = (half_t)fr,
               h3 = (half_t)fg, h4 = (half_t)fb;
        half8 fh = {h0, h1, h2, h3, h4, (half_t)0, (half_t)0, (half_t)0};
        *(half8*)(featH + (size_t)pl * FEATW) = fh;
        float a0 = (float)h0, a1 = (float)h1, a2 = (float)h2,
              a3 = (float)h3, a4 = (float)h4;
        sqF[pl] = 0.5f * (a0 * a0 + a1 * a1 + a2 * a2 + a3 * a3 + a4 * a4);
    } else if (q == 25) {
        if (pl < NSLOT) slots[pl * 16] = 0.0f;    // one slot per cacheline
    }
}

// ---------------------------------------------------------------------------
// Main: per 16x16 pair tile, two mfma_f32_16x16x32_f16:
//   E  = mfma(afeat, bfeat, c4)   with c4[r] = -h_i(row r) - h_j(col)
//   Gs = mfma(aseg,  bseg,  0)
//   term = exp2(E) * Gs     (diag blocks add {+1,0,-inf} in log2 space)
// Partials -> 64 spread cachelines (no same-address serialization, no
// device fence); crf_final sums them.  launch_bounds(256,8): VGPR=32 and
// LDS=17.9KB both allow 8 blocks/CU -- request full residency to hide the
// LDS->MFMA->exp2 latency chains (R7 showed the kernel ~80% idle).
// ---------------------------------------------------------------------------
__global__ __launch_bounds__(BLOCK, 8) void crf_main(const half_t* __restrict__ segH,
                                                     const half_t* __restrict__ featH,
                                                     const float* __restrict__ sqF,
                                                     float* __restrict__ slots) {
    const int bx = blockIdx.x;
    const int n  = blockIdx.y;

    // triangular decode: g = I>>2 group; 4 I's per group, 16-g J's each
    int g = 0;
#pragma unroll
    for (int t = 1; t < 16; ++t) {
        int off = 64 * t - 2 * t * (t - 1);
        if (bx >= off) g = t;
    }
    int rem = bx - (64 * g - 2 * g * (g - 1));
    int c   = 16 - g;
    int iq  = (rem >= c) + (rem >= 2 * c) + (rem >= 3 * c);
    int I   = 4 * g + iq;
    int J   = g + (rem - iq * c);
    const bool diag = (J == (I >> 2));

    const half_t* segN  = segH  + (size_t)n * PPX * SEGW;
    const half_t* featN = featH + (size_t)n * PPX * FEATW;
    const float*  sqN   = sqF   + (size_t)n * PPX;

    __shared__ alignas(16) half_t segJ[JCHUNK * SEGW];    // 12 KB
    __shared__ alignas(16) half_t featJ[JCHUNK * FEATW];  // 4 KB
    __shared__ alignas(16) half_t zrow[8];                // 16 B of zeros
    __shared__ float hJ[JCHUNK];                          // 1 KB
    __shared__ float wsum[BLOCK / 64];

    const int tid  = threadIdx.x;
    const int lane = tid & 63, wv = tid >> 6;
    const int m = lane & 15, quad = lane >> 4;
    const int i0 = I * IBLK + wv * 16;
    const int j0 = J * JCHUNK;
    const int kq = (quad < 2) ? quad : 2;   // seg k-slice (quad3 -> zero row)

    half8 hz = {};

    // A-frags from global (reused over all 16 j-tiles)
    half8 aseg  = *(const half8*)(segN  + (size_t)(i0 + m) * SEGW + kq * 8);
    half8 afeat = *(const half8*)(featN + (size_t)(i0 + m) * FEATW);
    f32x4v hi   = *(const f32x4v*)(sqN + i0 + quad * 4);  // rows quad*4..+3
    if (quad == 3) aseg  = hz;
    if (quad != 0) afeat = hz;
    f32x4v nh = -hi;

    // stage j-chunk (flat coalesced 16B copies) + zero row
    {
        const f32x4v* gsrc = (const f32x4v*)(segN + (size_t)j0 * SEGW);
        f32x4v* ldst = (f32x4v*)segJ;
#pragma unroll
        for (int v = 0; v < 3; ++v) ldst[tid + v * BLOCK] = gsrc[tid + v * BLOCK];
        ((f32x4v*)featJ)[tid] = ((const f32x4v*)(featN + (size_t)j0 * FEATW))[tid];
        hJ[tid] = sqN[j0 + tid];
        if (tid < 8) zrow[tid] = (half_t)0;
    }
    __syncthreads();

    // per-lane B pointers: stride over j-tiles, or pinned to the zero row
    const half_t* bsp; int bstep;
    if (quad == 3) { bsp = zrow;                       bstep = 0; }
    else           { bsp = segJ + m * SEGW + quad * 8; bstep = 16 * SEGW; }
    const half_t* bfp; int fstep;
    if (quad == 0) { bfp = featJ + m * FEATW;          fstep = 16 * FEATW; }
    else           { bfp = zrow;                       fstep = 0; }

    float racc = 0.0f;
    const f32x4v zero4 = {0.0f, 0.0f, 0.0f, 0.0f};

#pragma unroll 4
    for (int jt = 0; jt < JCHUNK / 16; ++jt) {
        half8 bseg = *(const half8*)bsp;  bsp += bstep;
        half8 bft  = *(const half8*)bfp;  bfp += fstep;
        float hc = hJ[jt * 16 + m];

        f32x4v c4 = {nh[0] - hc, nh[1] - hc, nh[2] - hc, nh[3] - hc};
        f32x4v E  = __builtin_amdgcn_mfma_f32_16x16x32_f16(afeat, bft, c4, 0, 0, 0);
        f32x4v Gs = __builtin_amdgcn_mfma_f32_16x16x32_f16(aseg, bseg, zero4, 0, 0, 0);

        if (!diag) {
#pragma unroll
            for (int r = 0; r < 4; ++r)
                racc = fmaf(__builtin_amdgcn_exp2f(E[r]), Gs[r], racc);
        } else {
            const int jg = j0 + jt * 16 + m;
#pragma unroll
            for (int r = 0; r < 4; ++r) {
                int ig = i0 + quad * 4 + r;
                float sel = (jg > ig) ? 1.0f : ((jg == ig) ? 0.0f : -100000.0f);
                racc = fmaf(__builtin_amdgcn_exp2f(E[r] + sel), Gs[r], racc);
            }
        }
    }

    // reduce: thread -> wave -> block -> spread atomic slot
#pragma unroll
    for (int off = 32; off > 0; off >>= 1) racc += __shfl_down(racc, off);
    if (lane == 0) wsum[wv] = racc;
    __syncthreads();
    if (tid == 0) {
        float s = wsum[0] + wsum[1] + wsum[2] + wsum[3];
        if (!diag) s *= 2.0f;              // strictly-upper counts (i,j)+(j,i)
        int slot = (bx + 544 * n) & (NSLOT - 1);
        atomicAdd(&slots[slot * 16], s);
    }
}

// ---------------------------------------------------------------------------
// Final: one wave sums the 64 slots and writes the scalar output.
// ---------------------------------------------------------------------------
__global__ __launch_bounds__(64) void crf_final(const float* __restrict__ slots,
                                                float* __restrict__ out) {
    int lane = threadIdx.x;
    float v = slots[lane * 16];
#pragma unroll
    for (int off = 32; off > 0; off >>= 1) v += __shfl_down(v, off);
    if (lane == 0) out[0] = v * (-5.0e-10f);   // WEIGHT * (-sum/NIMG)
}

extern "C" void kernel_launch(void* const* d_in, const int* in_sizes, int n_in,
                              void* d_out, int out_size, void* d_ws, size_t ws_size,
                              hipStream_t stream) {
    const float* img = (const float*)d_in[0];
    const float* seg = (const float*)d_in[1];
    const float* roi = (const float*)d_in[2];
    float* out = (float*)d_out;

    char* wsb = (char*)d_ws;                    // ~1.07 MB of ws used
    half_t* segH  = (half_t*)(wsb);
    half_t* featH = (half_t*)(wsb + FEATH_OFF);
    float*  sqF   = (float*)(wsb + SQF_OFF);
    float*  slots = (float*)(wsb + SLOT_OFF);

    crf_prep<<<(NPIX * 32) / BLOCK, BLOCK, 0, stream>>>(img, seg, roi,
                                                        segH, featH, sqF, slots);

    dim3 grid(544, NIMG);                       // sum_g 4*(16-g) = 544 per image
    crf_main<<<grid, BLOCK, 0, stream>>>(segH, featH, sqF, slots);

    crf_final<<<1, 64, 0, stream>>>(slots, out);
}